// Round 1
// baseline (735.137 us; speedup 1.0000x reference)
//
#include <hip/hip_runtime.h>

#define S_LEN 2048
#define NL 51
#define LS 53
#define ST 51
#define EN 52
#define NBATCH 256
#define L2E 1.4426950408889634f
#define LN2 0.6931471805599453f

typedef float f32x4 __attribute__((ext_vector_type(4)));

__device__ __forceinline__ float rlane(float v, int l) {
    return __builtin_bit_cast(float, __builtin_amdgcn_readlane(__builtin_bit_cast(int, v), l));
}

// One block per batch element, 2 waves.
// Wave 0: forward recursion, multiplicative domain, lagged divisor (math
// identical to prior rounds, all passed):
//   e_{t+1} = s_t * q_t,  s_t = E e_t,  q_t = gexp_t * rcp(ssum_{t-1}),
//   ssum = s[START]; applied divisors' log2 -> off2.
// R7: LDS-BROADCAST MATVEC. The 53 v_readlane broadcasts (suspected
// SGPR-writeback-throughput bound, ~6-7 cyc each even when batched) are
// replaced by 1 ds_write_b32 (lane j -> sh_e[j], stride-1, conflict-free)
// + 14 ds_read_b128 at a UNIFORM address: each read returns 4 broadcast
// scalars in 4 VGPRs (hardware same-address broadcast, conflict-free).
// The 14 reads are issued immediately after the ds_write so the LDS RTT
// overlaps the q-chain (log/rcp/exp2) and the logit prefetch. FMA
// operands are now all-VGPR (no SGPR write/read ports on the hot path).
// Only remaining readlane: 1x ssum = s[START] per step (off critical path).
// Wave 1: gold score (latency-tolerant global gathers), unchanged.
__global__ __launch_bounds__(128, 1) void crf_kernel(
    const float* __restrict__ logits,   // [256, 2048, 51]
    const int*   __restrict__ labels,   // [256, 2048]
    const int*   __restrict__ lens,     // [256]
    const float* __restrict__ Tr,       // [53, 53]  (to, from)
    float*       __restrict__ out)      // [256]
{
    const int b   = blockIdx.x;
    const int tid = threadIdx.x;
    const int len = lens[b];
    __shared__ float sh_gold;
    __shared__ float sh_norm;
    __shared__ f32x4 sh_e4[16];         // 64 floats: e broadcast buffer (wave 0 only)

    if (tid >= 64) {
        // ---- wave 1: gold score ----
        const int lid = tid - 64;
        const int* lb = labels + (long)b * S_LEN;
        const float* lg = logits + (long)b * S_LEN * NL;
        float p = 0.f;
        for (int t = lid; t < len; t += 64) {
            const int lab  = lb[t];
            const int prev = (t == 0) ? ST : lb[t - 1];
            p += lg[(long)t * NL + lab] + Tr[lab * LS + prev];
        }
        if (lid == 0) p += Tr[EN * LS + lb[len - 1]];   // final transition to END
#pragma unroll
        for (int off = 32; off > 0; off >>= 1)
            p += __shfl_down(p, off, 64);
        if (lid == 0) sh_gold = p;
    } else {
        // ---- wave 0: forward scan ----
        const int j  = tid;
        const int jj = (j < NL) ? j : 0;     // safe column for inactive lanes
        const float* trow = Tr + j * LS;
        float* sh_e = (float*)sh_e4;

        f32x4 er0, er1, er2, er3, er4, er5, er6, er7, er8, er9, er10, er11, er12, er13;
#define GT(K)    (((j < LS) && ((K) < LS)) ? trow[(K)] : -1e30f)
#define LD4(V,B) { V.x = GT(B); V.y = GT((B)+1); V.z = GT((B)+2); V.w = GT((B)+3); }
        LD4(er0, 0)  LD4(er1, 4)  LD4(er2, 8)   LD4(er3, 12)
        LD4(er4, 16) LD4(er5, 20) LD4(er6, 24)  LD4(er7, 28)
        LD4(er8, 32) LD4(er9, 36) LD4(er10, 40) LD4(er11, 44)
        LD4(er12, 48) LD4(er13, 52)
#undef GT
#undef LD4
        float tmax = -1e30f;
#define MX4(V) tmax = fmaxf(tmax, fmaxf(fmaxf(V.x, V.y), fmaxf(V.z, V.w)));
        MX4(er0) MX4(er1) MX4(er2) MX4(er3) MX4(er4) MX4(er5) MX4(er6)
        MX4(er7) MX4(er8) MX4(er9) MX4(er10) MX4(er11) MX4(er12) MX4(er13)
#undef MX4
        // er = exp(T - tmax). Lanes j>=53: tmax=-1e30 -> er=1, but their q
        // stays 0 (nl=-100, tmax=-1e30) so e stays 0 and they contribute 0
        // (their sh_e slots stay 0 and only B13.x=sh_e[52] is consumed anyway).
#define EX4(V) { V.x = __builtin_amdgcn_exp2f((V.x - tmax) * L2E); \
                 V.y = __builtin_amdgcn_exp2f((V.y - tmax) * L2E); \
                 V.z = __builtin_amdgcn_exp2f((V.z - tmax) * L2E); \
                 V.w = __builtin_amdgcn_exp2f((V.w - tmax) * L2E); }
        EX4(er0) EX4(er1) EX4(er2) EX4(er3) EX4(er4) EX4(er5) EX4(er6)
        EX4(er7) EX4(er8) EX4(er9) EX4(er10) EX4(er11) EX4(er12) EX4(er13)
#undef EX4

        const float* lg = logits + (long)b * S_LEN * NL;

        float buf[4];
        buf[0] = lg[0 * NL + jj];
        buf[1] = lg[1 * NL + jj];
        buf[2] = lg[2 * NL + jj];
        buf[3] = lg[3 * NL + jj];          // rows 0..3 always in-bounds (len>=1)

        float e     = (j == ST) ? 1.f : 0.f;   // exp(alpha0)
        float off2  = 0.f;                     // sum of log2 of APPLIED divisors
        float lprev = 0.f;                     // log2 of divisor inside current q
        float nl0   = (j < NL) ? buf[0] : -100.f;
        float q     = __builtin_amdgcn_exp2f((nl0 + tmax) * L2E);   // gexp_0

        // prime the broadcast buffer with e0 and load the first broadcasts
        sh_e[j] = e;
        f32x4 B0, B1, B2, B3, B4, B5, B6, B7, B8, B9, B10, B11, B12, B13;
#define LOADB { B0 = sh_e4[0];  B1 = sh_e4[1];  B2 = sh_e4[2];  B3 = sh_e4[3];  \
                B4 = sh_e4[4];  B5 = sh_e4[5];  B6 = sh_e4[6];  B7 = sh_e4[7];  \
                B8 = sh_e4[8];  B9 = sh_e4[9];  B10 = sh_e4[10]; B11 = sh_e4[11]; \
                B12 = sh_e4[12]; B13 = sh_e4[13]; }
        LOADB

#define FM4(BG, EV) { ax = fmaf(BG.x, EV.x, ax); ay = fmaf(BG.y, EV.y, ay); \
                      az = fmaf(BG.z, EV.z, az); aw = fmaf(BG.w, EV.w, aw); }
#define MATVEC(SOUT) { \
            float ax = 0.f, ay = 0.f, az = 0.f, aw = 0.f; \
            FM4(B0, er0) FM4(B1, er1) FM4(B2, er2) FM4(B3, er3) FM4(B4, er4) \
            FM4(B5, er5) FM4(B6, er6) FM4(B7, er7) FM4(B8, er8) FM4(B9, er9) \
            FM4(B10, er10) FM4(B11, er11) FM4(B12, er12) \
            ax = fmaf(B13.x, er13.x, ax); \
            SOUT = (ax + ay) + (az + aw); }

        // STEP: matvec from current broadcasts; publish new e; immediately
        // issue next step's broadcast reads (RTT hides under q-chain+prefetch).
#define STEP(NLRAW) { \
            float nl = (j < NL) ? (NLRAW) : -100.f; \
            float s; MATVEC(s); \
            e = s * q; \
            sh_e[j] = e; \
            LOADB \
            float ssum = rlane(s, ST); \
            off2 += lprev; \
            lprev = __builtin_amdgcn_logf(ssum); \
            q = __builtin_amdgcn_exp2f((nl + tmax) * L2E) * __builtin_amdgcn_rcpf(ssum); }

        int t = 0;
#pragma unroll 1
        while (t + 4 <= len) {
            {   // i = 0  (t+4 <= len <= 2047: in-bounds, no clamp)
                float pf = lg[(long)(t + 4) * NL + jj];
                STEP(buf[1])
                buf[0] = pf;
            }
            {   // i = 1
                int ti = t + 5; ti = (ti < S_LEN) ? ti : (S_LEN - 1);
                float pf = lg[(long)ti * NL + jj];
                STEP(buf[2])
                buf[1] = pf;
            }
            {   // i = 2
                int ti = t + 6; ti = (ti < S_LEN) ? ti : (S_LEN - 1);
                float pf = lg[(long)ti * NL + jj];
                STEP(buf[3])
                buf[2] = pf;
            }
            {   // i = 3
                int ti = t + 7; ti = (ti < S_LEN) ? ti : (S_LEN - 1);
                float pf = lg[(long)ti * NL + jj];
                STEP(buf[0])
                buf[3] = pf;
            }
            t += 4;
        }
        // tail: <= 3 steps; slot m holds row t+m; "next" logit of the last
        // step is in-bounds (row <= len <= 2047) and its q is never applied.
#pragma unroll
        for (int i = 0; i < 4; ++i) {
            if (t + i < len) {
                STEP(buf[(i + 1) & 3])
            }
        }

        // norm = logsumexp_j(alpha[j] + T[END, j]) : one more matvec, row END.
        // B currently holds broadcasts of the final e (last STEP's LOADB).
        float s; MATVEC(s);
        float sEnd  = rlane(s, EN);
        float tmEnd = rlane(tmax, EN);
        if (j == 0)
            sh_norm = (off2 + __builtin_amdgcn_logf(sEnd)) * LN2 + tmEnd;
#undef STEP
#undef MATVEC
#undef FM4
#undef LOADB
    }
    __syncthreads();
    if (tid == 0) out[b] = sh_gold - sh_norm;
}

extern "C" void kernel_launch(void* const* d_in, const int* in_sizes, int n_in,
                              void* d_out, int out_size, void* d_ws, size_t ws_size,
                              hipStream_t stream) {
    const float* logits = (const float*)d_in[0];
    const int*   labels = (const int*)d_in[1];
    const int*   lens   = (const int*)d_in[2];
    const float* Tr     = (const float*)d_in[3];
    float*       out    = (float*)d_out;
    crf_kernel<<<NBATCH, 128, 0, stream>>>(logits, labels, lens, Tr, out);
}